// Round 9
// baseline (1540.092 us; speedup 1.0000x reference)
//
#include <hip/hip_runtime.h>

typedef _Float16 h2 __attribute__((ext_vector_type(2)));
typedef unsigned int u32;

#define TB 1024

// ---- LDS layout (bytes) ----
// phase 1: A u32[6][34][34] @ 0       (27744)   h2 channel pairs
//          X f32[3][36][36] @ 27744   (15552)   dead after head
//          B u32[6][34][34] @ 27744   (27744)   overlays X -> end 55488
// phase 2: H u32[<=10][36][36] @ 0    (51840)   d-pair chunks, overlays all
// LDS_BYTES = 55488 per block (one 1024-thr block = 16 waves = 4 waves/SIMD,
// co-resident by construction -- R6 measured 47% occupancy).
#define XOFF_F 6936
#define BOFF_U 6936
#define LDS_BYTES 55488

__device__ __forceinline__ u32 packh2(float a, float b) {
    union { h2 h; u32 u; } v;
    v.h.x = (_Float16)a;
    v.h.y = (_Float16)b;
    return v.u;
}
__device__ __forceinline__ h2 as_h2(u32 u) {
    union { u32 u; h2 h; } v; v.u = u; return v.h;
}
__device__ __forceinline__ float fdot2(h2 a, h2 b, float c) {
    return __builtin_amdgcn_fdot2(a, b, c, false);   // v_dot2_f32_f16
}
__device__ __forceinline__ float prelu(float v, float a) {
    return (v >= 0.f) ? v : a * v;
}

// ---------------- weight pre-pack: fp32 -> fp16 pairs ----------------
// midp  : [4 layers][c:12][ep:6][ky:3][kx:3] u32 (pair = in-ch 2ep,2ep+1) = 2592
// tailp : [dp:28][ky:9][c:3][kx:9] u32          (pair = d 2dp,2dp+1)      = 6804
// b6p   : [d:56][sp:6] u32                      (pair = in-ch 2sp,2sp+1)  =  336
__global__ void pack_w(const float* __restrict__ b1_w, const float* __restrict__ b2_w,
                       const float* __restrict__ b3_w, const float* __restrict__ b4_w,
                       const float* __restrict__ tail_w, const float* __restrict__ b6_w,
                       u32* __restrict__ dst)
{
    const int i = blockIdx.x * blockDim.x + threadIdx.x;
    if (i < 2592) {
        const int L   = i / 648;
        const int rem = i - L * 648;          // (c*6+ep)*9 + ky*3 + kx
        const int c   = rem / 54;
        const int r2  = rem - c * 54;
        const int ep  = r2 / 9;
        const int k   = r2 - ep * 9;          // ky*3+kx
        const float* w = (L == 0) ? b1_w : (L == 1) ? b2_w : (L == 2) ? b3_w : b4_w;
        const float w0 = w[(c * 12 + 2 * ep) * 9 + k];
        const float w1 = w[(c * 12 + 2 * ep + 1) * 9 + k];
        dst[i] = packh2(w0, w1);
    } else if (i < 2592 + 6804) {
        const int t  = i - 2592;              // ((dp*9+ky)*3+c)*9+kx
        const int dp = t / 243;
        const int r2 = t - dp * 243;
        const int ky = r2 / 27;
        const int r3 = r2 - ky * 27;
        const int c  = r3 / 9;
        const int kx = r3 - c * 9;
        const float w0 = tail_w[((2 * dp)     * 3 + c) * 81 + ky * 9 + kx];
        const float w1 = tail_w[((2 * dp + 1) * 3 + c) * 81 + ky * 9 + kx];
        dst[2592 + t] = packh2(w0, w1);
    } else if (i < 2592 + 6804 + 336) {
        const int t = i - 9396;               // d*6 + sp
        const int d = t / 6;
        const int sp = t - d * 6;
        dst[9396 + t] = packh2(b6_w[d * 12 + 2 * sp], b6_w[d * 12 + 2 * sp + 1]);
    }
}

// VGPR ledger (this toolchain):
//  - Allocator sees dynamic LDS = 0 -> targets 2x1024-thr WGs/CU = 8 waves/EU
//    -> voluntarily caps 64 VGPR and SPILLS 3.7 GB (R6/R7/R8, 1490-1532 us).
//  - launch_bounds arg2 and amdgpu_waves_per_eu(4,4): both IGNORED (R7, R8).
//  - amdgpu_num_vgpr: HONORED (R3: forced 112 -> got 112; R4: 120 -> 120).
//  => force 128 here. The 16-wave block needs no scheduler favor (R6: 47%
//     occupancy already); 16 waves x 128 VGPR/CU co-reside per m69.
//     Pressure at 1 px/thread ~70-90 (R2: 2 px/thread fit under 128) -> headroom.
__global__ void __launch_bounds__(TB) __attribute__((amdgpu_num_vgpr(128)))
fsrcnn_fused(const float* __restrict__ x,
             const float* __restrict__ head_w, const float* __restrict__ head_b, const float* __restrict__ head_a,
             const float* __restrict__ b0_w, const float* __restrict__ b0_b, const float* __restrict__ b0_a,
             const float* __restrict__ b1_b, const float* __restrict__ b2_b,
             const float* __restrict__ b3_b, const float* __restrict__ b4_b,
             const float* __restrict__ b5_a,
             const float* __restrict__ b6_b, const float* __restrict__ b6_a,
             const float* __restrict__ tail_b,
             const u32* __restrict__ midp, const u32* __restrict__ tailp,
             const u32* __restrict__ b6p,
             float* __restrict__ out)
{
    extern __shared__ char smem[];
    u32*   const Au = reinterpret_cast<u32*>(smem);              // [6][34][34]
    float* const Xf = reinterpret_cast<float*>(smem) + XOFF_F;   // [3][36][36]
    u32*   const Bu = reinterpret_cast<u32*>(smem) + BOFF_U;     // [6][34][34]
    u32*   const Hw = reinterpret_cast<u32*>(smem);              // [<=10][36][36]

    const int tid = threadIdx.x;
    const int img = blockIdx.x;
    const int y   = tid >> 5;          // 0..31 pixel row
    const int x0  = tid & 31;          // 0..31 pixel col (1 px/thread)

    // ---------------- stage padded x (3x36x36) + zero A ----------------
    {
        const float* xg = x + img * 3072;
        for (int i = tid; i < 3888; i += TB) {
            const int c = i / 1296;
            const int rem = i - c * 1296;
            const int r = rem / 36;
            const int cl = rem - r * 36;
            const int iy = r - 2, ix = cl - 2;
            float v = 0.f;
            if ((unsigned)iy < 32u && (unsigned)ix < 32u)
                v = xg[(c << 10) + (iy << 5) + ix];
            Xf[i] = v;
        }
        uint4* az = reinterpret_cast<uint4*>(smem);
        const uint4 z4 = make_uint4(0u, 0u, 0u, 0u);
        for (int i = tid; i < 1734; i += TB) az[i] = z4;   // zero A (27744 B)
    }
    __syncthreads();

    // ---------------- head 5x5 3->56 + prelu + b0 1x1 56->12 + prelu -> A ----------------
    float accS[12];
    #pragma unroll
    for (int s = 0; s < 12; s++) accS[s] = b0_b[s];
    for (int d0 = 0; d0 < 56; d0 += 4) {
        float ah[4];
        #pragma unroll
        for (int dd = 0; dd < 4; dd++) ah[dd] = head_b[d0 + dd];
        #pragma unroll
        for (int ci = 0; ci < 3; ci++) {
            #pragma unroll
            for (int ky = 0; ky < 5; ky++) {
                const float* xr = &Xf[ci * 1296 + (y + ky) * 36 + x0];
                const float xv0 = xr[0], xv1 = xr[1], xv2 = xr[2], xv3 = xr[3], xv4 = xr[4];
                #pragma unroll
                for (int dd = 0; dd < 4; dd++) {
                    const float* wr = &head_w[((d0 + dd) * 3 + ci) * 25 + ky * 5];
                    ah[dd] = fmaf(xv0, wr[0], ah[dd]);
                    ah[dd] = fmaf(xv1, wr[1], ah[dd]);
                    ah[dd] = fmaf(xv2, wr[2], ah[dd]);
                    ah[dd] = fmaf(xv3, wr[3], ah[dd]);
                    ah[dd] = fmaf(xv4, wr[4], ah[dd]);
                }
            }
        }
        #pragma unroll
        for (int dd = 0; dd < 4; dd++) {
            const float v = prelu(ah[dd], head_a[d0 + dd]);
            #pragma unroll
            for (int s = 0; s < 12; s++)
                accS[s] = fmaf(b0_w[s * 56 + d0 + dd], v, accS[s]);
        }
    }
    #pragma unroll
    for (int sp = 0; sp < 6; sp++) {
        const float u = prelu(accS[2 * sp],     b0_a[2 * sp]);
        const float v = prelu(accS[2 * sp + 1], b0_a[2 * sp + 1]);
        Au[sp * 1156 + (y + 1) * 34 + x0 + 1] = packh2(u, v);
    }
    __syncthreads();

    // ---------------- zero B border (B overlays dead X) ----------------
    // b1 doesn't read B; the barrier after b1's writes publishes this to b2.
    for (int i = tid; i < 792; i += TB) {
        const int ch  = i / 132;
        const int rem = i - ch * 132;
        int row, col;
        if (rem < 68) { const int rr = rem / 34; row = rr * 33; col = rem - rr * 34; }
        else          { const int r2 = rem - 68; row = 1 + (r2 >> 1); col = (r2 & 1) * 33; }
        Bu[ch * 1156 + row * 34 + col] = 0u;
    }

    // ---------------- b1..b3: 3x3 12->12 pad1, dot2, LDS->LDS ----------------
    auto conv3h = [&](const u32* P, const u32* wp, const float* bias,
                      float* acc) {
        #pragma unroll
        for (int c = 0; c < 12; c++) acc[c] = bias[c];
        for (int ep = 0; ep < 6; ep++) {
            #pragma unroll
            for (int ky = 0; ky < 3; ky++) {
                const int idx = ep * 1156 + (y + ky) * 34 + x0;
                const u32 p0 = P[idx], p1 = P[idx + 1], p2 = P[idx + 2];
                const h2 xh0 = as_h2(p0), xh1 = as_h2(p1), xh2 = as_h2(p2);
                const u32* wr = wp + ep * 9 + ky * 3;
                #pragma unroll
                for (int c = 0; c < 12; c++) {
                    acc[c] = fdot2(xh0, as_h2(wr[c * 54 + 0]), acc[c]);
                    acc[c] = fdot2(xh1, as_h2(wr[c * 54 + 1]), acc[c]);
                    acc[c] = fdot2(xh2, as_h2(wr[c * 54 + 2]), acc[c]);
                }
            }
        }
    };
    {
        float acc[12];
        conv3h(Au, midp + 0, b1_b, acc);
        #pragma unroll
        for (int cp = 0; cp < 6; cp++)
            Bu[cp * 1156 + (y + 1) * 34 + x0 + 1] = packh2(acc[2 * cp], acc[2 * cp + 1]);
        __syncthreads();
        conv3h(Bu, midp + 648, b2_b, acc);
        #pragma unroll
        for (int cp = 0; cp < 6; cp++)
            Au[cp * 1156 + (y + 1) * 34 + x0 + 1] = packh2(acc[2 * cp], acc[2 * cp + 1]);
        __syncthreads();
        conv3h(Au, midp + 1296, b3_b, acc);
        #pragma unroll
        for (int cp = 0; cp < 6; cp++)
            Bu[cp * 1156 + (y + 1) * 34 + x0 + 1] = packh2(acc[2 * cp], acc[2 * cp + 1]);
        __syncthreads();
    }

    // ---------------- b4: 3x3 dot2 + prelu(b5_a) -> packed regs gp ----------------
    u32 gp[6];
    {
        float g[12];
        conv3h(Bu, midp + 1944, b4_b, g);
        #pragma unroll
        for (int sp = 0; sp < 6; sp++)
            gp[sp] = packh2(prelu(g[2 * sp],     b5_a[2 * sp]),
                            prelu(g[2 * sp + 1], b5_a[2 * sp + 1]));
    }
    __syncthreads();   // last reads of B done -> safe to overlay H

    // ---------------- b6 1x1 (dot2) + prelu -> H chunks {10,10,8} + tail ----------------
    float accT[2][3][2];
    {
        const float tb0 = tail_b[0], tb1 = tail_b[1], tb2 = tail_b[2];
        #pragma unroll
        for (int q = 0; q < 2; q++) {
            accT[0][0][q] = tb0; accT[0][1][q] = tb1; accT[0][2][q] = tb2;
            accT[1][0][q] = tb0; accT[1][1][q] = tb1; accT[1][2][q] = tb2;
        }
    }

    int dbase = 0;
    for (int ck = 0; ck < 3; ck++) {
        const int CNT = (ck == 2) ? 8 : 10;
        #pragma unroll 1
        for (int dpl = 0; dpl < CNT; dpl++) {
            const int d = (dbase + dpl) * 2;
            const u32* wb = b6p + d * 6;
            float va = b6_b[d], vb = b6_b[d + 1];
            #pragma unroll
            for (int sp = 0; sp < 6; sp++) {
                va = fdot2(as_h2(gp[sp]), as_h2(wb[sp]),     va);
                vb = fdot2(as_h2(gp[sp]), as_h2(wb[6 + sp]), vb);
            }
            va = prelu(va, b6_a[d]);
            vb = prelu(vb, b6_a[d + 1]);
            Hw[dpl * 1296 + (y + 2) * 36 + x0 + 2] = packh2(va, vb);
        }
        if (ck == 0) {
            // zero frame once for 10 pairs (chunks 1/2 reuse it)
            const uint2 z2 = make_uint2(0u, 0u);
            for (int i = tid; i < 720; i += TB) {      // rows 0,1,34,35
                const int dp = i / 72;
                const int rem = i - dp * 72;
                const int rr = rem / 18;
                const int cc = (rem - rr * 18) * 2;
                const int row = (rr & 1) + (rr >> 1) * 34;
                *reinterpret_cast<uint2*>(&Hw[dp * 1296 + row * 36 + cc]) = z2;
            }
            for (int i = tid; i < 640; i += TB) {      // cols 0,1 / 34,35, rows 2..33
                const int dp = i >> 6;
                const int rem = i & 63;
                const int row = 2 + (rem >> 1);
                const int col = (rem & 1) * 34;
                *reinterpret_cast<uint2*>(&Hw[dp * 1296 + row * 36 + col]) = z2;
            }
        }
        __syncthreads();

        // tail: 9x9 stride-2 convT, dot2 over d-pairs; H rows shared by both ry
        const u32* tw = tailp + dbase * 243;
        #pragma unroll
        for (int m = 0; m < 5; m++) {
            const int r = y + 4 - m;                    // padded row, in [0,35]
            #pragma unroll 1
            for (int dpl = 0; dpl < CNT; dpl++) {
                const int base = dpl * 1296 + r * 36 + x0;
                const u32 hh0 = Hw[base],     hh1 = Hw[base + 1], hh2 = Hw[base + 2];
                const u32 hh3 = Hw[base + 3], hh4 = Hw[base + 4];
                h2 xh[5] = { as_h2(hh0), as_h2(hh1), as_h2(hh2), as_h2(hh3), as_h2(hh4) };
                const u32* w0 = tw + dpl * 243 + (2 * m) * 27;   // ky = 2m   (ry=0)
                #pragma unroll
                for (int kx = 0; kx < 9; kx++) {
                    const int n = kx >> 1, rx = kx & 1;
                    #pragma unroll
                    for (int c = 0; c < 3; c++)
                        accT[0][c][rx] = fdot2(xh[4 - n], as_h2(w0[c * 9 + kx]), accT[0][c][rx]);
                }
                if (m < 4) {
                    const u32* w1 = w0 + 27;                     // ky = 2m+1 (ry=1)
                    #pragma unroll
                    for (int kx = 0; kx < 9; kx++) {
                        const int n = kx >> 1, rx = kx & 1;
                        #pragma unroll
                        for (int c = 0; c < 3; c++)
                            accT[1][c][rx] = fdot2(xh[4 - n], as_h2(w1[c * 9 + kx]), accT[1][c][rx]);
                    }
                }
            }
        }
        dbase += CNT;
        if (ck < 2) __syncthreads();   // chunk reads done before next overwrites H
    }

    // ---------------- store (2x2 output px per thread) ----------------
    #pragma unroll
    for (int ry = 0; ry < 2; ry++) {
        const int oy = 2 * y + ry;
        float* op = out + (img * 3) * 4096 + oy * 64 + 2 * x0;
        #pragma unroll
        for (int c = 0; c < 3; c++)
            *reinterpret_cast<float2*>(op + c * 4096) =
                make_float2(accT[ry][c][0], accT[ry][c][1]);
    }
}

extern "C" void kernel_launch(void* const* d_in, const int* in_sizes, int n_in,
                              void* d_out, int out_size, void* d_ws, size_t ws_size,
                              hipStream_t stream) {
    (void)in_sizes; (void)n_in; (void)ws_size; (void)out_size;
    const float* x      = (const float*)d_in[0];
    const float* head_w = (const float*)d_in[1];
    const float* head_b = (const float*)d_in[2];
    const float* head_a = (const float*)d_in[3];
    const float* b0_w   = (const float*)d_in[4];
    const float* b0_b   = (const float*)d_in[5];
    const float* b0_a   = (const float*)d_in[6];
    const float* b1_w   = (const float*)d_in[7];
    const float* b1_b   = (const float*)d_in[8];
    const float* b2_w   = (const float*)d_in[9];
    const float* b2_b   = (const float*)d_in[10];
    const float* b3_w   = (const float*)d_in[11];
    const float* b3_b   = (const float*)d_in[12];
    const float* b4_w   = (const float*)d_in[13];
    const float* b4_b   = (const float*)d_in[14];
    const float* b5_a   = (const float*)d_in[15];
    const float* b6_w   = (const float*)d_in[16];
    const float* b6_b   = (const float*)d_in[17];
    const float* b6_a   = (const float*)d_in[18];
    const float* tail_w = (const float*)d_in[19];
    const float* tail_b = (const float*)d_in[20];
    float* out = (float*)d_out;

    u32* wpk = (u32*)d_ws;   // 2592 mid + 6804 tail + 336 b6 = 9732 u32 = 38928 B
    pack_w<<<39, 256, 0, stream>>>(b1_w, b2_w, b3_w, b4_w, tail_w, b6_w, wpk);

    hipFuncSetAttribute(reinterpret_cast<const void*>(fsrcnn_fused),
                        hipFuncAttributeMaxDynamicSharedMemorySize, LDS_BYTES);
    fsrcnn_fused<<<1024, TB, LDS_BYTES, stream>>>(
        x, head_w, head_b, head_a, b0_w, b0_b, b0_a,
        b1_b, b2_b, b3_b, b4_b, b5_a,
        b6_b, b6_a, tail_b,
        wpk, wpk + 2592, wpk + 9396, out);
}

// Round 10
// 766.692 us; speedup vs baseline: 2.0087x; 2.0087x over previous
//
#include <hip/hip_runtime.h>

typedef _Float16 h2 __attribute__((ext_vector_type(2)));
typedef unsigned int u32;

#define TB 1024

// ---- LDS layout (bytes) ----
// phase 1: A u32[6][34][34] @ 0       (27744)   h2 channel pairs
//          X f32[3][36][36] @ 27744   (15552)   dead after head
//          B u32[6][34][34] @ 27744   (27744)   overlays X -> end 55488
// phase 2: H u32[<=10][36][36] @ 0    (51840)   d-pair chunks, overlays all
// LDS_BYTES = 55488; one 1024-thr block = 16 waves = 4 waves/SIMD (R6: 47% occ).
#define XOFF_F 6936
#define BOFF_U 6936
#define LDS_BYTES 55488

__device__ __forceinline__ u32 packh2(float a, float b) {
    union { h2 h; u32 u; } v;
    v.h.x = (_Float16)a;
    v.h.y = (_Float16)b;
    return v.u;
}
__device__ __forceinline__ h2 as_h2(u32 u) {
    union { u32 u; h2 h; } v; v.u = u; return v.h;
}
__device__ __forceinline__ float fdot2(h2 a, h2 b, float c) {
    return __builtin_amdgcn_fdot2(a, b, c, false);   // v_dot2_f32_f16
}
__device__ __forceinline__ float prelu(float v, float a) {
    return (v >= 0.f) ? v : a * v;
}

// ---------------- weight pre-pack: fp32 -> fp16 pairs ----------------
// midp  : [4 layers][c:12][ep:6][ky:3][kx:3] u32 (pair = in-ch 2ep,2ep+1) = 2592
// tailp : [dp:28][ky:9][c:3][kx:9] u32          (pair = d 2dp,2dp+1)      = 6804
// b6p   : [d:56][sp:6] u32                      (pair = in-ch 2sp,2sp+1)  =  336
__global__ void pack_w(const float* __restrict__ b1_w, const float* __restrict__ b2_w,
                       const float* __restrict__ b3_w, const float* __restrict__ b4_w,
                       const float* __restrict__ tail_w, const float* __restrict__ b6_w,
                       u32* __restrict__ dst)
{
    const int i = blockIdx.x * blockDim.x + threadIdx.x;
    if (i < 2592) {
        const int L   = i / 648;
        const int rem = i - L * 648;          // (c*6+ep)*9 + ky*3 + kx
        const int c   = rem / 54;
        const int r2  = rem - c * 54;
        const int ep  = r2 / 9;
        const int k   = r2 - ep * 9;          // ky*3+kx
        const float* w = (L == 0) ? b1_w : (L == 1) ? b2_w : (L == 2) ? b3_w : b4_w;
        const float w0 = w[(c * 12 + 2 * ep) * 9 + k];
        const float w1 = w[(c * 12 + 2 * ep + 1) * 9 + k];
        dst[i] = packh2(w0, w1);
    } else if (i < 2592 + 6804) {
        const int t  = i - 2592;              // ((dp*9+ky)*3+c)*9+kx
        const int dp = t / 243;
        const int r2 = t - dp * 243;
        const int ky = r2 / 27;
        const int r3 = r2 - ky * 27;
        const int c  = r3 / 9;
        const int kx = r3 - c * 9;
        const float w0 = tail_w[((2 * dp)     * 3 + c) * 81 + ky * 9 + kx];
        const float w1 = tail_w[((2 * dp + 1) * 3 + c) * 81 + ky * 9 + kx];
        dst[2592 + t] = packh2(w0, w1);
    } else if (i < 2592 + 6804 + 336) {
        const int t = i - 9396;               // d*6 + sp
        const int d = t / 6;
        const int sp = t - d * 6;
        dst[9396 + t] = packh2(b6_w[d * 12 + 2 * sp], b6_w[d * 12 + 2 * sp + 1]);
    }
}

// VGPR ledger, final form (this toolchain):
//  TB=1024 -> allocator pins 64 VGPR no matter what: launch_bounds arg2 (R7),
//  amdgpu_waves_per_eu(4,4) (R8), amdgpu_num_vgpr(128) (R9) ALL ignored
//  (num_vgpr IS honored at TB=512 -- R3/R4). So: make 64 enough.
//  R6-R9's 3.7 GB spills = unroll bloat (full unroll of d0/ci/ky/ep hoists
//  ~75 LDS loads into one live web), NOT algorithmic state (~30-40 regs at
//  1 px/thread). #pragma unroll 1 on the heavy loops collapses the web
//  (R4 precedent: same fix dropped pressure 125+ -> <=120 at 2 px/thread).
__global__ void __launch_bounds__(TB)
fsrcnn_fused(const float* __restrict__ x,
             const float* __restrict__ head_w, const float* __restrict__ head_b, const float* __restrict__ head_a,
             const float* __restrict__ b0_w, const float* __restrict__ b0_b, const float* __restrict__ b0_a,
             const float* __restrict__ b1_b, const float* __restrict__ b2_b,
             const float* __restrict__ b3_b, const float* __restrict__ b4_b,
             const float* __restrict__ b5_a,
             const float* __restrict__ b6_b, const float* __restrict__ b6_a,
             const float* __restrict__ tail_b,
             const u32* __restrict__ midp, const u32* __restrict__ tailp,
             const u32* __restrict__ b6p,
             float* __restrict__ out)
{
    extern __shared__ char smem[];
    u32*   const Au = reinterpret_cast<u32*>(smem);              // [6][34][34]
    float* const Xf = reinterpret_cast<float*>(smem) + XOFF_F;   // [3][36][36]
    u32*   const Bu = reinterpret_cast<u32*>(smem) + BOFF_U;     // [6][34][34]
    u32*   const Hw = reinterpret_cast<u32*>(smem);              // [<=10][36][36]

    const int tid = threadIdx.x;
    const int img = blockIdx.x;
    const int y   = tid >> 5;          // 0..31 pixel row
    const int x0  = tid & 31;          // 0..31 pixel col (1 px/thread)

    // ---------------- stage padded x (3x36x36) + zero A ----------------
    {
        const float* xg = x + img * 3072;
        for (int i = tid; i < 3888; i += TB) {
            const int c = i / 1296;
            const int rem = i - c * 1296;
            const int r = rem / 36;
            const int cl = rem - r * 36;
            const int iy = r - 2, ix = cl - 2;
            float v = 0.f;
            if ((unsigned)iy < 32u && (unsigned)ix < 32u)
                v = xg[(c << 10) + (iy << 5) + ix];
            Xf[i] = v;
        }
        uint4* az = reinterpret_cast<uint4*>(smem);
        const uint4 z4 = make_uint4(0u, 0u, 0u, 0u);
        for (int i = tid; i < 1734; i += TB) az[i] = z4;   // zero A (27744 B)
    }
    __syncthreads();

    // ---------------- head 5x5 3->56 + prelu + b0 1x1 56->12 + prelu -> A ----------------
    float accS[12];
    #pragma unroll
    for (int s = 0; s < 12; s++) accS[s] = b0_b[s];
    #pragma unroll 1
    for (int d0 = 0; d0 < 56; d0 += 4) {
        float ah[4];
        #pragma unroll
        for (int dd = 0; dd < 4; dd++) ah[dd] = head_b[d0 + dd];
        #pragma unroll 1
        for (int ci = 0; ci < 3; ci++) {
            #pragma unroll 1
            for (int ky = 0; ky < 5; ky++) {
                const float* xr = &Xf[ci * 1296 + (y + ky) * 36 + x0];
                const float xv0 = xr[0], xv1 = xr[1], xv2 = xr[2], xv3 = xr[3], xv4 = xr[4];
                #pragma unroll
                for (int dd = 0; dd < 4; dd++) {
                    const float* wr = &head_w[((d0 + dd) * 3 + ci) * 25 + ky * 5];
                    ah[dd] = fmaf(xv0, wr[0], ah[dd]);
                    ah[dd] = fmaf(xv1, wr[1], ah[dd]);
                    ah[dd] = fmaf(xv2, wr[2], ah[dd]);
                    ah[dd] = fmaf(xv3, wr[3], ah[dd]);
                    ah[dd] = fmaf(xv4, wr[4], ah[dd]);
                }
            }
        }
        #pragma unroll
        for (int dd = 0; dd < 4; dd++) {
            const float v = prelu(ah[dd], head_a[d0 + dd]);
            #pragma unroll
            for (int s = 0; s < 12; s++)
                accS[s] = fmaf(b0_w[s * 56 + d0 + dd], v, accS[s]);
        }
    }
    #pragma unroll
    for (int sp = 0; sp < 6; sp++) {
        const float u = prelu(accS[2 * sp],     b0_a[2 * sp]);
        const float v = prelu(accS[2 * sp + 1], b0_a[2 * sp + 1]);
        Au[sp * 1156 + (y + 1) * 34 + x0 + 1] = packh2(u, v);
    }
    __syncthreads();

    // ---------------- zero B border (B overlays dead X) ----------------
    // b1 doesn't read B; the barrier after b1's writes publishes this to b2.
    for (int i = tid; i < 792; i += TB) {
        const int ch  = i / 132;
        const int rem = i - ch * 132;
        int row, col;
        if (rem < 68) { const int rr = rem / 34; row = rr * 33; col = rem - rr * 34; }
        else          { const int r2 = rem - 68; row = 1 + (r2 >> 1); col = (r2 & 1) * 33; }
        Bu[ch * 1156 + row * 34 + col] = 0u;
    }

    // ---------------- b1..b3: 3x3 12->12 pad1, dot2, LDS->LDS ----------------
    auto conv3h = [&](const u32* P, const u32* wp, const float* bias,
                      float* acc) {
        #pragma unroll
        for (int c = 0; c < 12; c++) acc[c] = bias[c];
        #pragma unroll 1
        for (int ep = 0; ep < 6; ep++) {
            #pragma unroll
            for (int ky = 0; ky < 3; ky++) {
                const int idx = ep * 1156 + (y + ky) * 34 + x0;
                const u32 p0 = P[idx], p1 = P[idx + 1], p2 = P[idx + 2];
                const h2 xh0 = as_h2(p0), xh1 = as_h2(p1), xh2 = as_h2(p2);
                const u32* wr = wp + ep * 9 + ky * 3;
                #pragma unroll
                for (int c = 0; c < 12; c++) {
                    acc[c] = fdot2(xh0, as_h2(wr[c * 54 + 0]), acc[c]);
                    acc[c] = fdot2(xh1, as_h2(wr[c * 54 + 1]), acc[c]);
                    acc[c] = fdot2(xh2, as_h2(wr[c * 54 + 2]), acc[c]);
                }
            }
        }
    };
    {
        float acc[12];
        conv3h(Au, midp + 0, b1_b, acc);
        #pragma unroll
        for (int cp = 0; cp < 6; cp++)
            Bu[cp * 1156 + (y + 1) * 34 + x0 + 1] = packh2(acc[2 * cp], acc[2 * cp + 1]);
        __syncthreads();
        conv3h(Bu, midp + 648, b2_b, acc);
        #pragma unroll
        for (int cp = 0; cp < 6; cp++)
            Au[cp * 1156 + (y + 1) * 34 + x0 + 1] = packh2(acc[2 * cp], acc[2 * cp + 1]);
        __syncthreads();
        conv3h(Au, midp + 1296, b3_b, acc);
        #pragma unroll
        for (int cp = 0; cp < 6; cp++)
            Bu[cp * 1156 + (y + 1) * 34 + x0 + 1] = packh2(acc[2 * cp], acc[2 * cp + 1]);
        __syncthreads();
    }

    // ---------------- b4: 3x3 dot2 + prelu(b5_a) -> packed regs gp ----------------
    u32 gp[6];
    {
        float g[12];
        conv3h(Bu, midp + 1944, b4_b, g);
        #pragma unroll
        for (int sp = 0; sp < 6; sp++)
            gp[sp] = packh2(prelu(g[2 * sp],     b5_a[2 * sp]),
                            prelu(g[2 * sp + 1], b5_a[2 * sp + 1]));
    }
    __syncthreads();   // last reads of B done -> safe to overlay H

    // ---------------- b6 1x1 (dot2) + prelu -> H chunks {10,10,8} + tail ----------------
    float accT[2][3][2];
    {
        const float tb0 = tail_b[0], tb1 = tail_b[1], tb2 = tail_b[2];
        #pragma unroll
        for (int q = 0; q < 2; q++) {
            accT[0][0][q] = tb0; accT[0][1][q] = tb1; accT[0][2][q] = tb2;
            accT[1][0][q] = tb0; accT[1][1][q] = tb1; accT[1][2][q] = tb2;
        }
    }

    int dbase = 0;
    #pragma unroll 1
    for (int ck = 0; ck < 3; ck++) {
        const int CNT = (ck == 2) ? 8 : 10;
        #pragma unroll 1
        for (int dpl = 0; dpl < CNT; dpl++) {
            const int d = (dbase + dpl) * 2;
            const u32* wb = b6p + d * 6;
            float va = b6_b[d], vb = b6_b[d + 1];
            #pragma unroll
            for (int sp = 0; sp < 6; sp++) {
                va = fdot2(as_h2(gp[sp]), as_h2(wb[sp]),     va);
                vb = fdot2(as_h2(gp[sp]), as_h2(wb[6 + sp]), vb);
            }
            va = prelu(va, b6_a[d]);
            vb = prelu(vb, b6_a[d + 1]);
            Hw[dpl * 1296 + (y + 2) * 36 + x0 + 2] = packh2(va, vb);
        }
        if (ck == 0) {
            // zero frame once for 10 pairs (chunks 1/2 reuse it)
            const uint2 z2 = make_uint2(0u, 0u);
            for (int i = tid; i < 720; i += TB) {      // rows 0,1,34,35
                const int dp = i / 72;
                const int rem = i - dp * 72;
                const int rr = rem / 18;
                const int cc = (rem - rr * 18) * 2;
                const int row = (rr & 1) + (rr >> 1) * 34;
                *reinterpret_cast<uint2*>(&Hw[dp * 1296 + row * 36 + cc]) = z2;
            }
            for (int i = tid; i < 640; i += TB) {      // cols 0,1 / 34,35, rows 2..33
                const int dp = i >> 6;
                const int rem = i & 63;
                const int row = 2 + (rem >> 1);
                const int col = (rem & 1) * 34;
                *reinterpret_cast<uint2*>(&Hw[dp * 1296 + row * 36 + col]) = z2;
            }
        }
        __syncthreads();

        // tail: 9x9 stride-2 convT, dot2 over d-pairs; H rows shared by both ry
        const u32* tw = tailp + dbase * 243;
        #pragma unroll 1
        for (int m = 0; m < 5; m++) {
            const int r = y + 4 - m;                    // padded row, in [0,35]
            #pragma unroll 1
            for (int dpl = 0; dpl < CNT; dpl++) {
                const int base = dpl * 1296 + r * 36 + x0;
                const u32 hh0 = Hw[base],     hh1 = Hw[base + 1], hh2 = Hw[base + 2];
                const u32 hh3 = Hw[base + 3], hh4 = Hw[base + 4];
                h2 xh[5] = { as_h2(hh0), as_h2(hh1), as_h2(hh2), as_h2(hh3), as_h2(hh4) };
                const u32* w0 = tw + dpl * 243 + (2 * m) * 27;   // ky = 2m   (ry=0)
                #pragma unroll
                for (int kx = 0; kx < 9; kx++) {
                    const int n = kx >> 1, rx = kx & 1;
                    #pragma unroll
                    for (int c = 0; c < 3; c++)
                        accT[0][c][rx] = fdot2(xh[4 - n], as_h2(w0[c * 9 + kx]), accT[0][c][rx]);
                }
                if (m < 4) {
                    const u32* w1 = w0 + 27;                     // ky = 2m+1 (ry=1)
                    #pragma unroll
                    for (int kx = 0; kx < 9; kx++) {
                        const int n = kx >> 1, rx = kx & 1;
                        #pragma unroll
                        for (int c = 0; c < 3; c++)
                            accT[1][c][rx] = fdot2(xh[4 - n], as_h2(w1[c * 9 + kx]), accT[1][c][rx]);
                    }
                }
            }
        }
        dbase += CNT;
        if (ck < 2) __syncthreads();   // chunk reads done before next overwrites H
    }

    // ---------------- store (2x2 output px per thread) ----------------
    #pragma unroll
    for (int ry = 0; ry < 2; ry++) {
        const int oy = 2 * y + ry;
        float* op = out + (img * 3) * 4096 + oy * 64 + 2 * x0;
        #pragma unroll
        for (int c = 0; c < 3; c++)
            *reinterpret_cast<float2*>(op + c * 4096) =
                make_float2(accT[ry][c][0], accT[ry][c][1]);
    }
}

extern "C" void kernel_launch(void* const* d_in, const int* in_sizes, int n_in,
                              void* d_out, int out_size, void* d_ws, size_t ws_size,
                              hipStream_t stream) {
    (void)in_sizes; (void)n_in; (void)ws_size; (void)out_size;
    const float* x      = (const float*)d_in[0];
    const float* head_w = (const float*)d_in[1];
    const float* head_b = (const float*)d_in[2];
    const float* head_a = (const float*)d_in[3];
    const float* b0_w   = (const float*)d_in[4];
    const float* b0_b   = (const float*)d_in[5];
    const float* b0_a   = (const float*)d_in[6];
    const float* b1_w   = (const float*)d_in[7];
    const float* b1_b   = (const float*)d_in[8];
    const float* b2_w   = (const float*)d_in[9];
    const float* b2_b   = (const float*)d_in[10];
    const float* b3_w   = (const float*)d_in[11];
    const float* b3_b   = (const float*)d_in[12];
    const float* b4_w   = (const float*)d_in[13];
    const float* b4_b   = (const float*)d_in[14];
    const float* b5_a   = (const float*)d_in[15];
    const float* b6_w   = (const float*)d_in[16];
    const float* b6_b   = (const float*)d_in[17];
    const float* b6_a   = (const float*)d_in[18];
    const float* tail_w = (const float*)d_in[19];
    const float* tail_b = (const float*)d_in[20];
    float* out = (float*)d_out;

    u32* wpk = (u32*)d_ws;   // 2592 mid + 6804 tail + 336 b6 = 9732 u32 = 38928 B
    pack_w<<<39, 256, 0, stream>>>(b1_w, b2_w, b3_w, b4_w, tail_w, b6_w, wpk);

    hipFuncSetAttribute(reinterpret_cast<const void*>(fsrcnn_fused),
                        hipFuncAttributeMaxDynamicSharedMemorySize, LDS_BYTES);
    fsrcnn_fused<<<1024, TB, LDS_BYTES, stream>>>(
        x, head_w, head_b, head_a, b0_w, b0_b, b0_a,
        b1_b, b2_b, b3_b, b4_b, b5_a,
        b6_b, b6_a, tail_b,
        wpk, wpk + 2592, wpk + 9396, out);
}

// Round 11
// 755.214 us; speedup vs baseline: 2.0393x; 1.0152x over previous
//
#include <hip/hip_runtime.h>

typedef _Float16 h2 __attribute__((ext_vector_type(2)));
typedef unsigned int u32;

#define TB 1024

// ---- LDS layout (bytes) ----
// phase 1: A u32[6][34][34] @ 0       (27744)   h2 channel pairs
//          X f32[3][36][36] @ 27744   (15552)   dead after head
//          B u32[6][34][34] @ 27744   (27744)   overlays X -> end 55488
// phase 2: H u32[<=10][36][36] @ 0    (51840)   d-pair chunks, overlays all
// LDS_BYTES = 55488; one 1024-thr block = 16 waves = 4 waves/SIMD (47% occ).
#define XOFF_F 6936
#define BOFF_U 6936
#define LDS_BYTES 55488

__device__ __forceinline__ u32 packh2(float a, float b) {
    union { h2 h; u32 u; } v;
    v.h.x = (_Float16)a;
    v.h.y = (_Float16)b;
    return v.u;
}
__device__ __forceinline__ h2 as_h2(u32 u) {
    union { u32 u; h2 h; } v; v.u = u; return v.h;
}
__device__ __forceinline__ float fdot2(h2 a, h2 b, float c) {
    return __builtin_amdgcn_fdot2(a, b, c, false);   // v_dot2_f32_f16
}
__device__ __forceinline__ float prelu(float v, float a) {
    return (v >= 0.f) ? v : a * v;
}

// ---------------- weight pre-pack: fp32 -> fp16 pairs ----------------
// midp  : [4 layers][c:12][ep:6][ky:3][kx:3] u32 (pair = in-ch 2ep,2ep+1) = 2592
// tailp : [dp:28][ky:9][c:3][kx:9] u32          (pair = d 2dp,2dp+1)      = 6804
// b6p   : [d:56][sp:6] u32                      (pair = in-ch 2sp,2sp+1)  =  336
__global__ void pack_w(const float* __restrict__ b1_w, const float* __restrict__ b2_w,
                       const float* __restrict__ b3_w, const float* __restrict__ b4_w,
                       const float* __restrict__ tail_w, const float* __restrict__ b6_w,
                       u32* __restrict__ dst)
{
    const int i = blockIdx.x * blockDim.x + threadIdx.x;
    if (i < 2592) {
        const int L   = i / 648;
        const int rem = i - L * 648;          // (c*6+ep)*9 + ky*3 + kx
        const int c   = rem / 54;
        const int r2  = rem - c * 54;
        const int ep  = r2 / 9;
        const int k   = r2 - ep * 9;          // ky*3+kx
        const float* w = (L == 0) ? b1_w : (L == 1) ? b2_w : (L == 2) ? b3_w : b4_w;
        const float w0 = w[(c * 12 + 2 * ep) * 9 + k];
        const float w1 = w[(c * 12 + 2 * ep + 1) * 9 + k];
        dst[i] = packh2(w0, w1);
    } else if (i < 2592 + 6804) {
        const int t  = i - 2592;              // ((dp*9+ky)*3+c)*9+kx
        const int dp = t / 243;
        const int r2 = t - dp * 243;
        const int ky = r2 / 27;
        const int r3 = r2 - ky * 27;
        const int c  = r3 / 9;
        const int kx = r3 - c * 9;
        const float w0 = tail_w[((2 * dp)     * 3 + c) * 81 + ky * 9 + kx];
        const float w1 = tail_w[((2 * dp + 1) * 3 + c) * 81 + ky * 9 + kx];
        dst[2592 + t] = packh2(w0, w1);
    } else if (i < 2592 + 6804 + 336) {
        const int t = i - 9396;               // d*6 + sp
        const int d = t / 6;
        const int sp = t - d * 6;
        dst[9396 + t] = packh2(b6_w[d * 12 + 2 * sp], b6_w[d * 12 + 2 * sp + 1]);
    }
}

// Register-budget ledger (this toolchain): TB=1024 pins a 64-VGPR cap
// (launch_bounds arg2 / waves_per_eu / num_vgpr ALL ignored at TB=1024;
// R7-R9). R10: unroll 1 everywhere -> VGPR 20, NO spills, 47% occ, 725 us,
// but VALUBusy 52% (zero ILP slack; serial LDS->wait->dot2 chains).
// R11: spend the 44 spare regs on 2-deep software pipelining: unroll 2 on
// {conv3h ep, tail dpl, b6 dpl, head ky}. Outer loops (d0, ci, m, ck) stay
// unroll 1 -- full unroll of those was R6's 75-reg load web that spilled.
__global__ void __launch_bounds__(TB)
fsrcnn_fused(const float* __restrict__ x,
             const float* __restrict__ head_w, const float* __restrict__ head_b, const float* __restrict__ head_a,
             const float* __restrict__ b0_w, const float* __restrict__ b0_b, const float* __restrict__ b0_a,
             const float* __restrict__ b1_b, const float* __restrict__ b2_b,
             const float* __restrict__ b3_b, const float* __restrict__ b4_b,
             const float* __restrict__ b5_a,
             const float* __restrict__ b6_b, const float* __restrict__ b6_a,
             const float* __restrict__ tail_b,
             const u32* __restrict__ midp, const u32* __restrict__ tailp,
             const u32* __restrict__ b6p,
             float* __restrict__ out)
{
    extern __shared__ char smem[];
    u32*   const Au = reinterpret_cast<u32*>(smem);              // [6][34][34]
    float* const Xf = reinterpret_cast<float*>(smem) + XOFF_F;   // [3][36][36]
    u32*   const Bu = reinterpret_cast<u32*>(smem) + BOFF_U;     // [6][34][34]
    u32*   const Hw = reinterpret_cast<u32*>(smem);              // [<=10][36][36]

    const int tid = threadIdx.x;
    const int img = blockIdx.x;
    const int y   = tid >> 5;          // 0..31 pixel row
    const int x0  = tid & 31;          // 0..31 pixel col (1 px/thread)

    // ---------------- stage padded x (3x36x36) + zero A ----------------
    {
        const float* xg = x + img * 3072;
        for (int i = tid; i < 3888; i += TB) {
            const int c = i / 1296;
            const int rem = i - c * 1296;
            const int r = rem / 36;
            const int cl = rem - r * 36;
            const int iy = r - 2, ix = cl - 2;
            float v = 0.f;
            if ((unsigned)iy < 32u && (unsigned)ix < 32u)
                v = xg[(c << 10) + (iy << 5) + ix];
            Xf[i] = v;
        }
        uint4* az = reinterpret_cast<uint4*>(smem);
        const uint4 z4 = make_uint4(0u, 0u, 0u, 0u);
        for (int i = tid; i < 1734; i += TB) az[i] = z4;   // zero A (27744 B)
    }
    __syncthreads();

    // ---------------- head 5x5 3->56 + prelu + b0 1x1 56->12 + prelu -> A ----------------
    float accS[12];
    #pragma unroll
    for (int s = 0; s < 12; s++) accS[s] = b0_b[s];
    #pragma unroll 1
    for (int d0 = 0; d0 < 56; d0 += 4) {
        float ah[4];
        #pragma unroll
        for (int dd = 0; dd < 4; dd++) ah[dd] = head_b[d0 + dd];
        #pragma unroll 1
        for (int ci = 0; ci < 3; ci++) {
            #pragma unroll 2
            for (int ky = 0; ky < 5; ky++) {
                const float* xr = &Xf[ci * 1296 + (y + ky) * 36 + x0];
                const float xv0 = xr[0], xv1 = xr[1], xv2 = xr[2], xv3 = xr[3], xv4 = xr[4];
                #pragma unroll
                for (int dd = 0; dd < 4; dd++) {
                    const float* wr = &head_w[((d0 + dd) * 3 + ci) * 25 + ky * 5];
                    ah[dd] = fmaf(xv0, wr[0], ah[dd]);
                    ah[dd] = fmaf(xv1, wr[1], ah[dd]);
                    ah[dd] = fmaf(xv2, wr[2], ah[dd]);
                    ah[dd] = fmaf(xv3, wr[3], ah[dd]);
                    ah[dd] = fmaf(xv4, wr[4], ah[dd]);
                }
            }
        }
        #pragma unroll
        for (int dd = 0; dd < 4; dd++) {
            const float v = prelu(ah[dd], head_a[d0 + dd]);
            #pragma unroll
            for (int s = 0; s < 12; s++)
                accS[s] = fmaf(b0_w[s * 56 + d0 + dd], v, accS[s]);
        }
    }
    #pragma unroll
    for (int sp = 0; sp < 6; sp++) {
        const float u = prelu(accS[2 * sp],     b0_a[2 * sp]);
        const float v = prelu(accS[2 * sp + 1], b0_a[2 * sp + 1]);
        Au[sp * 1156 + (y + 1) * 34 + x0 + 1] = packh2(u, v);
    }
    __syncthreads();

    // ---------------- zero B border (B overlays dead X) ----------------
    // b1 doesn't read B; the barrier after b1's writes publishes this to b2.
    for (int i = tid; i < 792; i += TB) {
        const int ch  = i / 132;
        const int rem = i - ch * 132;
        int row, col;
        if (rem < 68) { const int rr = rem / 34; row = rr * 33; col = rem - rr * 34; }
        else          { const int r2 = rem - 68; row = 1 + (r2 >> 1); col = (r2 & 1) * 33; }
        Bu[ch * 1156 + row * 34 + col] = 0u;
    }

    // ---------------- b1..b3: 3x3 12->12 pad1, dot2, LDS->LDS ----------------
    auto conv3h = [&](const u32* P, const u32* wp, const float* bias,
                      float* acc) {
        #pragma unroll
        for (int c = 0; c < 12; c++) acc[c] = bias[c];
        #pragma unroll 2
        for (int ep = 0; ep < 6; ep++) {
            #pragma unroll
            for (int ky = 0; ky < 3; ky++) {
                const int idx = ep * 1156 + (y + ky) * 34 + x0;
                const u32 p0 = P[idx], p1 = P[idx + 1], p2 = P[idx + 2];
                const h2 xh0 = as_h2(p0), xh1 = as_h2(p1), xh2 = as_h2(p2);
                const u32* wr = wp + ep * 9 + ky * 3;
                #pragma unroll
                for (int c = 0; c < 12; c++) {
                    acc[c] = fdot2(xh0, as_h2(wr[c * 54 + 0]), acc[c]);
                    acc[c] = fdot2(xh1, as_h2(wr[c * 54 + 1]), acc[c]);
                    acc[c] = fdot2(xh2, as_h2(wr[c * 54 + 2]), acc[c]);
                }
            }
        }
    };
    {
        float acc[12];
        conv3h(Au, midp + 0, b1_b, acc);
        #pragma unroll
        for (int cp = 0; cp < 6; cp++)
            Bu[cp * 1156 + (y + 1) * 34 + x0 + 1] = packh2(acc[2 * cp], acc[2 * cp + 1]);
        __syncthreads();
        conv3h(Bu, midp + 648, b2_b, acc);
        #pragma unroll
        for (int cp = 0; cp < 6; cp++)
            Au[cp * 1156 + (y + 1) * 34 + x0 + 1] = packh2(acc[2 * cp], acc[2 * cp + 1]);
        __syncthreads();
        conv3h(Au, midp + 1296, b3_b, acc);
        #pragma unroll
        for (int cp = 0; cp < 6; cp++)
            Bu[cp * 1156 + (y + 1) * 34 + x0 + 1] = packh2(acc[2 * cp], acc[2 * cp + 1]);
        __syncthreads();
    }

    // ---------------- b4: 3x3 dot2 + prelu(b5_a) -> packed regs gp ----------------
    u32 gp[6];
    {
        float g[12];
        conv3h(Bu, midp + 1944, b4_b, g);
        #pragma unroll
        for (int sp = 0; sp < 6; sp++)
            gp[sp] = packh2(prelu(g[2 * sp],     b5_a[2 * sp]),
                            prelu(g[2 * sp + 1], b5_a[2 * sp + 1]));
    }
    __syncthreads();   // last reads of B done -> safe to overlay H

    // ---------------- b6 1x1 (dot2) + prelu -> H chunks {10,10,8} + tail ----------------
    float accT[2][3][2];
    {
        const float tb0 = tail_b[0], tb1 = tail_b[1], tb2 = tail_b[2];
        #pragma unroll
        for (int q = 0; q < 2; q++) {
            accT[0][0][q] = tb0; accT[0][1][q] = tb1; accT[0][2][q] = tb2;
            accT[1][0][q] = tb0; accT[1][1][q] = tb1; accT[1][2][q] = tb2;
        }
    }

    int dbase = 0;
    #pragma unroll 1
    for (int ck = 0; ck < 3; ck++) {
        const int CNT = (ck == 2) ? 8 : 10;
        #pragma unroll 2
        for (int dpl = 0; dpl < CNT; dpl++) {
            const int d = (dbase + dpl) * 2;
            const u32* wb = b6p + d * 6;
            float va = b6_b[d], vb = b6_b[d + 1];
            #pragma unroll
            for (int sp = 0; sp < 6; sp++) {
                va = fdot2(as_h2(gp[sp]), as_h2(wb[sp]),     va);
                vb = fdot2(as_h2(gp[sp]), as_h2(wb[6 + sp]), vb);
            }
            va = prelu(va, b6_a[d]);
            vb = prelu(vb, b6_a[d + 1]);
            Hw[dpl * 1296 + (y + 2) * 36 + x0 + 2] = packh2(va, vb);
        }
        if (ck == 0) {
            // zero frame once for 10 pairs (chunks 1/2 reuse it)
            const uint2 z2 = make_uint2(0u, 0u);
            for (int i = tid; i < 720; i += TB) {      // rows 0,1,34,35
                const int dp = i / 72;
                const int rem = i - dp * 72;
                const int rr = rem / 18;
                const int cc = (rem - rr * 18) * 2;
                const int row = (rr & 1) + (rr >> 1) * 34;
                *reinterpret_cast<uint2*>(&Hw[dp * 1296 + row * 36 + cc]) = z2;
            }
            for (int i = tid; i < 640; i += TB) {      // cols 0,1 / 34,35, rows 2..33
                const int dp = i >> 6;
                const int rem = i & 63;
                const int row = 2 + (rem >> 1);
                const int col = (rem & 1) * 34;
                *reinterpret_cast<uint2*>(&Hw[dp * 1296 + row * 36 + col]) = z2;
            }
        }
        __syncthreads();

        // tail: 9x9 stride-2 convT, dot2 over d-pairs; H rows shared by both ry
        const u32* tw = tailp + dbase * 243;
        #pragma unroll 1
        for (int m = 0; m < 5; m++) {
            const int r = y + 4 - m;                    // padded row, in [0,35]
            #pragma unroll 2
            for (int dpl = 0; dpl < CNT; dpl++) {
                const int base = dpl * 1296 + r * 36 + x0;
                const u32 hh0 = Hw[base],     hh1 = Hw[base + 1], hh2 = Hw[base + 2];
                const u32 hh3 = Hw[base + 3], hh4 = Hw[base + 4];
                h2 xh[5] = { as_h2(hh0), as_h2(hh1), as_h2(hh2), as_h2(hh3), as_h2(hh4) };
                const u32* w0 = tw + dpl * 243 + (2 * m) * 27;   // ky = 2m   (ry=0)
                #pragma unroll
                for (int kx = 0; kx < 9; kx++) {
                    const int n = kx >> 1, rx = kx & 1;
                    #pragma unroll
                    for (int c = 0; c < 3; c++)
                        accT[0][c][rx] = fdot2(xh[4 - n], as_h2(w0[c * 9 + kx]), accT[0][c][rx]);
                }
                if (m < 4) {
                    const u32* w1 = w0 + 27;                     // ky = 2m+1 (ry=1)
                    #pragma unroll
                    for (int kx = 0; kx < 9; kx++) {
                        const int n = kx >> 1, rx = kx & 1;
                        #pragma unroll
                        for (int c = 0; c < 3; c++)
                            accT[1][c][rx] = fdot2(xh[4 - n], as_h2(w1[c * 9 + kx]), accT[1][c][rx]);
                    }
                }
            }
        }
        dbase += CNT;
        if (ck < 2) __syncthreads();   // chunk reads done before next overwrites H
    }

    // ---------------- store (2x2 output px per thread) ----------------
    #pragma unroll
    for (int ry = 0; ry < 2; ry++) {
        const int oy = 2 * y + ry;
        float* op = out + (img * 3) * 4096 + oy * 64 + 2 * x0;
        #pragma unroll
        for (int c = 0; c < 3; c++)
            *reinterpret_cast<float2*>(op + c * 4096) =
                make_float2(accT[ry][c][0], accT[ry][c][1]);
    }
}

extern "C" void kernel_launch(void* const* d_in, const int* in_sizes, int n_in,
                              void* d_out, int out_size, void* d_ws, size_t ws_size,
                              hipStream_t stream) {
    (void)in_sizes; (void)n_in; (void)ws_size; (void)out_size;
    const float* x      = (const float*)d_in[0];
    const float* head_w = (const float*)d_in[1];
    const float* head_b = (const float*)d_in[2];
    const float* head_a = (const float*)d_in[3];
    const float* b0_w   = (const float*)d_in[4];
    const float* b0_b   = (const float*)d_in[5];
    const float* b0_a   = (const float*)d_in[6];
    const float* b1_w   = (const float*)d_in[7];
    const float* b1_b   = (const float*)d_in[8];
    const float* b2_w   = (const float*)d_in[9];
    const float* b2_b   = (const float*)d_in[10];
    const float* b3_w   = (const float*)d_in[11];
    const float* b3_b   = (const float*)d_in[12];
    const float* b4_w   = (const float*)d_in[13];
    const float* b4_b   = (const float*)d_in[14];
    const float* b5_a   = (const float*)d_in[15];
    const float* b6_w   = (const float*)d_in[16];
    const float* b6_b   = (const float*)d_in[17];
    const float* b6_a   = (const float*)d_in[18];
    const float* tail_w = (const float*)d_in[19];
    const float* tail_b = (const float*)d_in[20];
    float* out = (float*)d_out;

    u32* wpk = (u32*)d_ws;   // 2592 mid + 6804 tail + 336 b6 = 9732 u32 = 38928 B
    pack_w<<<39, 256, 0, stream>>>(b1_w, b2_w, b3_w, b4_w, tail_w, b6_w, wpk);

    hipFuncSetAttribute(reinterpret_cast<const void*>(fsrcnn_fused),
                        hipFuncAttributeMaxDynamicSharedMemorySize, LDS_BYTES);
    fsrcnn_fused<<<1024, TB, LDS_BYTES, stream>>>(
        x, head_w, head_b, head_a, b0_w, b0_b, b0_a,
        b1_b, b2_b, b3_b, b4_b, b5_a,
        b6_b, b6_a, tail_b,
        wpk, wpk + 2592, wpk + 9396, out);
}